// Round 12
// baseline (1533.207 us; speedup 1.0000x reference)
//
#include <hip/hip_runtime.h>
#include <hip/hip_bf16.h>

#define B_ 8
#define S_ 2048
#define D_ 1024
#define SCALE 0.03125f   // 1/sqrt(1024)
#define NT_ (D_ / 64)    // K-tiles of 64

typedef __attribute__((ext_vector_type(4))) float f32x4;
typedef __attribute__((ext_vector_type(8))) short short8;
typedef __attribute__((ext_vector_type(4))) short short4v;

static __device__ inline unsigned short f2bf(float f) {
    unsigned int u = __float_as_uint(f);
    u += 0x7FFF + ((u >> 16) & 1);     // round-to-nearest-even
    return (unsigned short)(u >> 16);
}

static __device__ __forceinline__ void gload16(const void* g, void* l) {
    __builtin_amdgcn_global_load_lds(
        (const __attribute__((address_space(1))) unsigned int*)g,
        (__attribute__((address_space(3))) unsigned int*)l, 16, 0, 0);
}

static __device__ __forceinline__ void pipe_sync() {
    asm volatile("s_waitcnt vmcnt(0)" ::: "memory");
    __builtin_amdgcn_s_barrier();
    __builtin_amdgcn_sched_barrier(0);
}

// XCD-aware bijective swizzle (nwg divisible by 8).  [T1]
static __device__ __forceinline__ int xcd_swz(int hw, int nwg) {
    return (hw & 7) * (nwg >> 3) + (hw >> 3);
}

// Bank swizzle for [rows][64]bf16 (128B rows): XOR col-slot bits [6:4] with
// row&7 -> 16 same-col lanes land on 8 distinct 16B slots (2-way = free). [T2]
static __device__ __forceinline__ int swz(int byte) {
    return byte ^ (((byte >> 7) & 7) << 4);
}

// ---------------------------------------------------------------- lengths ---
__global__ void lengths_kernel(const unsigned char* __restrict__ pm, int* __restrict__ lens) {
    __shared__ int cnt[B_];
    int tid = threadIdx.x;
    if (tid < B_) cnt[tid] = 0;
    __syncthreads();
    int layout;
    if (pm[0] == 1 && pm[1] == 1) layout = 0;        // bool/uint8
    else if (pm[0] == 1) layout = 1;                 // int32
    else layout = 2;                                 // float32
    for (int i = tid; i < B_ * S_; i += blockDim.x) {
        bool v;
        if (layout == 0) v = pm[i] != 0;
        else if (layout == 1) v = ((const int*)pm)[i] != 0;
        else v = ((const float*)pm)[i] != 0.0f;
        if (v) atomicAdd(&cnt[i >> 11], 1);
    }
    __syncthreads();
    if (tid < B_) lens[tid] = cnt[tid];
}

// ---------------------------------------------------------------- convert ---
__global__ void convert_all_kernel(const float* __restrict__ q, const float* __restrict__ k,
                                   const float* __restrict__ v,
                                   const float* __restrict__ Wq, const float* __restrict__ Wk,
                                   const float* __restrict__ Wv,
                                   unsigned short* __restrict__ Xb,
                                   unsigned short* __restrict__ Wb) {
    const int z = blockIdx.z;
    const float* src;
    unsigned short* dst;
    int n;
    if (z < 3) {
        src = (z == 0) ? q : (z == 1) ? k : v;
        dst = Xb + (size_t)z * B_ * S_ * D_;
        n = B_ * S_ * D_;
    } else {
        src = (z == 3) ? Wq : (z == 4) ? Wk : Wv;
        dst = Wb + (size_t)(z - 3) * D_ * D_;
        n = D_ * D_;
    }
    int idx = (blockIdx.x * 256 + threadIdx.x) * 8;
    if (idx >= n) return;
    float4 a = *(const float4*)(src + idx);
    float4 b = *(const float4*)(src + idx + 4);
    short8 o;
    o[0] = (short)f2bf(a.x); o[1] = (short)f2bf(a.y);
    o[2] = (short)f2bf(a.z); o[3] = (short)f2bf(a.w);
    o[4] = (short)f2bf(b.x); o[5] = (short)f2bf(b.y);
    o[6] = (short)f2bf(b.z); o[7] = (short)f2bf(b.w);
    *(short8*)(dst + idx) = o;
}

// ---------------------------------------------------------------- proj 256^2
// Single-buffer 64KB LDS -> 2 blocks/CU (cross-block overlap hides the
// stage->vmcnt->barrier stall, m114 mechanism).  Straight-line tile compute.
__global__ __launch_bounds__(512, 4) void proj2_kernel(
        const unsigned short* __restrict__ Xb3,
        const unsigned short* __restrict__ Wb3,
        const float* __restrict__ bq, const float* __restrict__ bk,
        const float* __restrict__ bv,
        unsigned short* __restrict__ Qb,
        unsigned short* __restrict__ Kb,
        unsigned short* __restrict__ Vt) {
    const int nwg = 3 * (B_ * S_ / 256) * (D_ / 256);   // 768
    const int log_id = xcd_swz(blockIdx.x, nwg);
    const int z = log_id >> 8;                          // 256 blocks per z
    const int rem = log_id & 255;
    const int m0 = (rem >> 2) * 256;
    const int n0 = (rem & 3) * 256;

    const unsigned short* Xb = Xb3 + (size_t)z * B_ * S_ * D_;
    const unsigned short* Wb = Wb3 + (size_t)z * D_ * D_;
    const float* bias = (z == 0) ? bq : (z == 1) ? bk : bv;

    // [A=0/B=1][half][128*64] bf16 = 64 KB (single buffer)
    __shared__ unsigned short lds[2][2][128 * 64];

    const int tid = threadIdx.x;
    const int lane = tid & 63, wid = tid >> 6;
    const int wm = wid >> 2, wn = wid & 3;       // 2M x 4N waves; wave tile 128x64
    const int g = lane >> 4, l15 = lane & 15;

    // staging: linear LDS dest (rule #21); GLOBAL source column pre-swizzled.
    const int f0 = tid * 16;
    const int r0s = f0 >> 7, c0s = f0 & 127;
    const int csrc = c0s ^ ((r0s & 7) << 4);   // row&7 invariant under +64

    f32x4 acc[8][4];
    const f32x4 z4 = {0.f, 0.f, 0.f, 0.f};
#pragma unroll
    for (int a = 0; a < 8; ++a)
#pragma unroll
        for (int b2 = 0; b2 < 4; ++b2) acc[a][b2] = z4;

    auto stageT = [&](int kk) {
#pragma unroll
        for (int h = 0; h < 2; ++h) {
            gload16((const char*)Xb + ((size_t)(m0 + h * 128 + r0s) * D_ + kk) * 2 + csrc,
                    (char*)&lds[0][h][0] + f0);
            gload16((const char*)Xb + ((size_t)(m0 + h * 128 + r0s + 64) * D_ + kk) * 2 + csrc,
                    (char*)&lds[0][h][0] + f0 + 8192);
            gload16((const char*)Wb + ((size_t)(n0 + h * 128 + r0s) * D_ + kk) * 2 + csrc,
                    (char*)&lds[1][h][0] + f0);
            gload16((const char*)Wb + ((size_t)(n0 + h * 128 + r0s + 64) * D_ + kk) * 2 + csrc,
                    (char*)&lds[1][h][0] + f0 + 8192);
        }
    };

    for (int T = 0; T < NT_; ++T) {
        stageT(T * 64);
        pipe_sync();                         // loads resident for all waves
        const char* Abase = (const char*)&lds[0][wm][0];
#pragma unroll
        for (int ks = 0; ks < 2; ++ks) {
            const int colb = ks * 64 + g * 16;
            short8 bfr[4], afr[8];
#pragma unroll
            for (int nf = 0; nf < 4; ++nf) {
                int nl = wn * 64 + nf * 16 + l15;
                bfr[nf] = *(const short8*)((const char*)&lds[1][nl >> 7][0]
                                           + swz((nl & 127) * 128 + colb));
            }
#pragma unroll
            for (int mf = 0; mf < 8; ++mf)
                afr[mf] = *(const short8*)(Abase + swz((mf * 16 + l15) * 128 + colb));
            __builtin_amdgcn_s_setprio(1);
#pragma unroll
            for (int mf = 0; mf < 8; ++mf)
#pragma unroll
                for (int nf = 0; nf < 4; ++nf)
                    acc[mf][nf] = __builtin_amdgcn_mfma_f32_16x16x32_bf16(
                        afr[mf], bfr[nf], acc[mf][nf], 0, 0, 0);
            __builtin_amdgcn_s_setprio(0);
        }
        __builtin_amdgcn_s_barrier();        // reads of buffer done before next stage
    }

    if (z < 2) {
        unsigned short* O = (z == 0) ? Qb : Kb;
#pragma unroll
        for (int mf = 0; mf < 8; ++mf) {
#pragma unroll
            for (int nf = 0; nf < 4; ++nf) {
                int gm = m0 + wm * 128 + mf * 16 + 4 * g;
                int gn = n0 + wn * 64 + nf * 16 + l15;
                float bb = bias[gn];
#pragma unroll
                for (int i = 0; i < 4; ++i)
                    O[(size_t)(gm + i) * D_ + gn] = f2bf(acc[mf][nf][i] + bb);
            }
        }
    } else {
#pragma unroll
        for (int mf = 0; mf < 8; ++mf) {
#pragma unroll
            for (int nf = 0; nf < 4; ++nf) {
                int gm = m0 + wm * 128 + mf * 16 + 4 * g;   // flat token
                int b = gm >> 11, tok = gm & 2047;
                int gn = n0 + wn * 64 + nf * 16 + l15;
                float bb = bias[gn];
                short4v sv;
#pragma unroll
                for (int i = 0; i < 4; ++i) sv[i] = (short)f2bf(acc[mf][nf][i] + bb);
                *(short4v*)(&Vt[((size_t)b * D_ + gn) * S_ + tok]) = sv;
            }
        }
    }
}

// ------------------------------------------------- proj (fused conv, fallback)
__global__ void proj_kernel(const float* __restrict__ q, const float* __restrict__ k,
                            const float* __restrict__ v,
                            const float* __restrict__ Wq, const float* __restrict__ Wk,
                            const float* __restrict__ Wv,
                            const float* __restrict__ bq, const float* __restrict__ bk,
                            const float* __restrict__ bv,
                            unsigned short* __restrict__ Qb, unsigned short* __restrict__ Kb,
                            unsigned short* __restrict__ Vt) {
    const int z = blockIdx.z;
    const float* X = (z == 0) ? q : (z == 1) ? k : v;
    const float* W = (z == 0) ? Wq : (z == 1) ? Wk : Wv;
    const float* bias = (z == 0) ? bq : (z == 1) ? bk : bv;

    __shared__ short As[128 * 40];
    __shared__ short Bs[128 * 40];

    const int m0 = blockIdx.y * 128;
    const int n0 = blockIdx.x * 128;
    const int tid = threadIdx.x;
    const int lane = tid & 63, wid = tid >> 6;
    const int wr = wid >> 1, wc = wid & 1;
    const int g = lane >> 4, l15 = lane & 15;

    f32x4 acc[4][4];
    const f32x4 z4 = {0.f, 0.f, 0.f, 0.f};
    for (int a = 0; a < 4; ++a)
        for (int b2 = 0; b2 < 4; ++b2) acc[a][b2] = z4;

    for (int kk = 0; kk < D_; kk += 32) {
#pragma unroll
        for (int it = 0; it < 4; ++it) {
            int flat = it * 1024 + tid * 4;
            int r = flat >> 5, c = flat & 31;
            float4 va = *(const float4*)(X + (size_t)(m0 + r) * D_ + kk + c);
            short4v sa = {(short)f2bf(va.x), (short)f2bf(va.y), (short)f2bf(va.z), (short)f2bf(va.w)};
            *(short4v*)(&As[r * 40 + c]) = sa;
            float4 vb = *(const float4*)(W + (size_t)(n0 + r) * D_ + kk + c);
            short4v sb = {(short)f2bf(vb.x), (short)f2bf(vb.y), (short)f2bf(vb.z), (short)f2bf(vb.w)};
            *(short4v*)(&Bs[r * 40 + c]) = sb;
        }
        __syncthreads();
        short8 a_frag[4], b_frag[4];
#pragma unroll
        for (int mf = 0; mf < 4; ++mf)
            a_frag[mf] = *(const short8*)(&As[(wr * 64 + mf * 16 + l15) * 40 + g * 8]);
#pragma unroll
        for (int nf = 0; nf < 4; ++nf)
            b_frag[nf] = *(const short8*)(&Bs[(wc * 64 + nf * 16 + l15) * 40 + g * 8]);
#pragma unroll
        for (int mf = 0; mf < 4; ++mf)
#pragma unroll
            for (int nf = 0; nf < 4; ++nf)
                acc[mf][nf] = __builtin_amdgcn_mfma_f32_16x16x32_bf16(a_frag[mf], b_frag[nf], acc[mf][nf], 0, 0, 0);
        __syncthreads();
    }

    if (z < 2) {
        unsigned short* O = (z == 0) ? Qb : Kb;
#pragma unroll
        for (int mf = 0; mf < 4; ++mf) {
#pragma unroll
            for (int nf = 0; nf < 4; ++nf) {
                int gm = m0 + wr * 64 + mf * 16 + 4 * g;
                int gn = n0 + wc * 64 + nf * 16 + l15;
                float bb = bias[gn];
#pragma unroll
                for (int i = 0; i < 4; ++i)
                    O[(size_t)(gm + i) * D_ + gn] = f2bf(acc[mf][nf][i] + bb);
            }
        }
    } else {
#pragma unroll
        for (int mf = 0; mf < 4; ++mf) {
#pragma unroll
            for (int nf = 0; nf < 4; ++nf) {
                int gm = m0 + wr * 64 + mf * 16 + 4 * g;
                int b = gm >> 11, tok = gm & 2047;
                int gn = n0 + wc * 64 + nf * 16 + l15;
                float bb = bias[gn];
                short4v sv;
#pragma unroll
                for (int i = 0; i < 4; ++i) sv[i] = (short)f2bf(acc[mf][nf][i] + bb);
                *(short4v*)(&Vt[((size_t)b * D_ + gn) * S_ + tok]) = sv;
            }
        }
    }
}

// ---------------------------------------------------------------- scores ----
// Causal-tiled GEMM, BK=64 [128][64] swizzled LDS, 1 barrier per K-tile.
__global__ void scores_kernel(const unsigned short* __restrict__ Qb,
                              const unsigned short* __restrict__ Kb,
                              const int* __restrict__ lens,
                              float* __restrict__ attn) {
    const int log_id = xcd_swz(blockIdx.x, 136 * B_);
    const int b = log_id / 136;
    const int idx = log_id - b * 136;
    int qt = (int)((sqrtf(8.f * idx + 1.f) - 1.f) * 0.5f);
    while ((qt + 1) * (qt + 2) / 2 <= idx) ++qt;
    while (qt * (qt + 1) / 2 > idx) --qt;
    const int kt = idx - qt * (qt + 1) / 2;
    const int m0 = qt * 128, n0 = kt * 128;
    const int len = lens[b];
    if (m0 >= len) return;

    __shared__ unsigned short As[2][128 * 64];   // 2 x 16 KB
    __shared__ unsigned short Bs[2][128 * 64];

    const int tid = threadIdx.x;
    const int lane = tid & 63, w = tid >> 6;
    const int wr = w >> 1, wc = w & 1;
    const int g = lane >> 4, l15 = lane & 15;

    const char* Qbase = (const char*)(Qb + (size_t)(b * S_ + m0) * D_);
    const char* Kbase = (const char*)(Kb + (size_t)(b * S_ + n0) * D_);

    const int f0 = tid * 16;                 // 0..4080
    const int rs = f0 >> 7, cs = f0 & 127;   // rows 0..31
    const int csrc = cs ^ ((rs & 7) << 4);   // row&7 invariant under +32

    auto stage = [&](int buf, int kk) {
#pragma unroll
        for (int c = 0; c < 4; ++c) {
            gload16(Qbase + (size_t)(rs + c * 32) * (D_ * 2) + kk * 2 + csrc,
                    (char*)&As[buf][0] + c * 4096 + f0);
            gload16(Kbase + (size_t)(rs + c * 32) * (D_ * 2) + kk * 2 + csrc,
                    (char*)&Bs[buf][0] + c * 4096 + f0);
        }
    };

    f32x4 acc[4][4];
    const f32x4 z4 = {0.f, 0.f, 0.f, 0.f};
    for (int a = 0; a < 4; ++a)
        for (int b2 = 0; b2 < 4; ++b2) acc[a][b2] = z4;

    stage(0, 0);
    pipe_sync();
    for (int T = 0; T < NT_; ++T) {
        const int cur = T & 1;
        if (T + 1 < NT_) stage(cur ^ 1, (T + 1) * 64);
#pragma unroll
        for (int ks = 0; ks < 2; ++ks) {
            const int colb = ks * 64 + g * 16;
            short8 a_frag[4], b_frag[4];
#pragma unroll
            for (int mf = 0; mf < 4; ++mf)
                a_frag[mf] = *(const short8*)((const char*)&As[cur][0]
                                              + swz((wr * 64 + mf * 16 + l15) * 128 + colb));
#pragma unroll
            for (int nf = 0; nf < 4; ++nf)
                b_frag[nf] = *(const short8*)((const char*)&Bs[cur][0]
                                              + swz((wc * 64 + nf * 16 + l15) * 128 + colb));
            __builtin_amdgcn_s_setprio(1);
#pragma unroll
            for (int mf = 0; mf < 4; ++mf)
#pragma unroll
                for (int nf = 0; nf < 4; ++nf)
                    acc[mf][nf] = __builtin_amdgcn_mfma_f32_16x16x32_bf16(
                        a_frag[mf], b_frag[nf], acc[mf][nf], 0, 0, 0);
            __builtin_amdgcn_s_setprio(0);
        }
        pipe_sync();
    }

    const bool interior = (m0 >= n0 + 128) && (m0 + 128 <= len);
    if (interior) {
#pragma unroll
        for (int mf = 0; mf < 4; ++mf) {
#pragma unroll
            for (int nf = 0; nf < 4; ++nf) {
                int gm = m0 + wr * 64 + mf * 16 + 4 * g;
                int gn = n0 + wc * 64 + nf * 16 + l15;
#pragma unroll
                for (int i = 0; i < 4; ++i)
                    attn[(size_t)(b * S_ + gm + i) * S_ + gn] = acc[mf][nf][i] * SCALE;
            }
        }
    } else {
#pragma unroll
        for (int mf = 0; mf < 4; ++mf) {
#pragma unroll
            for (int nf = 0; nf < 4; ++nf) {
                int gm = m0 + wr * 64 + mf * 16 + 4 * g;
                int gn = n0 + wc * 64 + nf * 16 + l15;
#pragma unroll
                for (int i = 0; i < 4; ++i) {
                    int rq = gm + i;
                    if (rq < len && gn <= rq)
                        attn[(size_t)(b * S_ + rq) * S_ + gn] = acc[mf][nf][i] * SCALE;
                }
            }
        }
    }
}

// ---------------------------------------------------------------- softmax ---
__global__ void softmax_kernel(const int* __restrict__ lens,
                               float* __restrict__ attn, unsigned short* __restrict__ P) {
    const int row = blockIdx.x;
    const int b = row >> 11, qpos = row & 2047;
    const int tid = threadIdx.x;
    const size_t rbase = (size_t)row * S_;
    const int c0 = tid * 8;
    const short8 zp = {0, 0, 0, 0, 0, 0, 0, 0};
    const float4 zf = {0.f, 0.f, 0.f, 0.f};
    if (qpos >= lens[b]) {
        *(short8*)(&P[rbase + c0]) = zp;
        *(float4*)(attn + rbase + c0) = zf;
        *(float4*)(attn + rbase + c0 + 4) = zf;
        return;
    }
    __shared__ float wm[4], wl[4];
    const bool act = (c0 <= qpos);
    float x[8];
    if (act) {
        float4 a0 = *(const float4*)(attn + rbase + c0);
        float4 a1 = *(const float4*)(attn + rbase + c0 + 4);
        x[0] = a0.x; x[1] = a0.y; x[2] = a0.z; x[3] = a0.w;
        x[4] = a1.x; x[5] = a1.y; x[6] = a1.z; x[7] = a1.w;
#pragma unroll
        for (int j = 0; j < 8; ++j)
            if (c0 + j > qpos) x[j] = -1e30f;
    } else {
#pragma unroll
        for (int j = 0; j < 8; ++j) x[j] = -1e30f;
    }
    float lmax = -1e30f;
#pragma unroll
    for (int j = 0; j < 8; ++j) lmax = fmaxf(lmax, x[j]);
#pragma unroll
    for (int off = 1; off < 64; off <<= 1) lmax = fmaxf(lmax, __shfl_xor(lmax, off));
    if ((tid & 63) == 0) wm[tid >> 6] = lmax;
    __syncthreads();
    const float m = fmaxf(fmaxf(wm[0], wm[1]), fmaxf(wm[2], wm[3]));
    float e[8];
    float lsum = 0.f;
#pragma unroll
    for (int j = 0; j < 8; ++j) {
        e[j] = (x[j] > -1e29f) ? __expf(x[j] - m) : 0.f;
        lsum += e[j];
    }
#pragma unroll
    for (int off = 1; off < 64; off <<= 1) lsum += __shfl_xor(lsum, off);
    if ((tid & 63) == 0) wl[tid >> 6] = lsum;
    __syncthreads();
    if (act) {
        const float inv = 1.0f / (wl[0] + wl[1] + wl[2] + wl[3]);
        float4 o0, o1;
        short8 pb;
#pragma unroll
        for (int j = 0; j < 8; ++j) {
            e[j] *= inv;
            pb[j] = (short)f2bf(e[j]);
        }
        o0.x = e[0]; o0.y = e[1]; o0.z = e[2]; o0.w = e[3];
        o1.x = e[4]; o1.y = e[5]; o1.z = e[6]; o1.w = e[7];
        *(float4*)(attn + rbase + c0) = o0;
        *(float4*)(attn + rbase + c0 + 4) = o1;
        *(short8*)(&P[rbase + c0]) = pb;
    } else {
        *(float4*)(attn + rbase + c0) = zf;
        *(float4*)(attn + rbase + c0 + 4) = zf;
        *(short8*)(&P[rbase + c0]) = zp;
    }
}

// ---------------------------------------------------------------- PV --------
// BK=64 [128][64] swizzled LDS, 1 barrier per K-tile.
__global__ void pv_kernel(const unsigned short* __restrict__ P,
                          const unsigned short* __restrict__ Vt,
                          const int* __restrict__ lens, float* __restrict__ seq) {
    const int log_id = xcd_swz(blockIdx.x, B_ * (S_ / 128) * (D_ / 128));
    const int b = log_id >> 7;
    const int rem = log_id & 127;
    const int q0 = (rem >> 3) * 128;
    const int n0 = (rem & 7) * 128;
    const int len = lens[b];
    const int tid = threadIdx.x;

    if (q0 >= len) {
        const float4 zf = {0.f, 0.f, 0.f, 0.f};
#pragma unroll
        for (int it = 0; it < 16; ++it) {
            int flat = it * 1024 + tid * 4;
            int r = flat >> 7, c = flat & 127;
            *(float4*)(&seq[(size_t)(b * S_ + q0 + r) * D_ + n0 + c]) = zf;
        }
        return;
    }

    __shared__ unsigned short As[2][128 * 64];
    __shared__ unsigned short Bs[2][128 * 64];
    const int lane = tid & 63, w = tid >> 6;
    const int wr = w >> 1, wc = w & 1;
    const int g = lane >> 4, l15 = lane & 15;

    const char* Pbase = (const char*)(P + (size_t)(b * S_ + q0) * S_);
    const char* Vbase = (const char*)(Vt + ((size_t)b * D_ + n0) * S_);

    const int f0 = tid * 16;
    const int rs = f0 >> 7, cs = f0 & 127;
    const int csrc = cs ^ ((rs & 7) << 4);

    auto stage = [&](int buf, int kk) {
#pragma unroll
        for (int c = 0; c < 4; ++c) {
            gload16(Pbase + (size_t)(rs + c * 32) * (S_ * 2) + kk * 2 + csrc,
                    (char*)&As[buf][0] + c * 4096 + f0);
            gload16(Vbase + (size_t)(rs + c * 32) * (S_ * 2) + kk * 2 + csrc,
                    (char*)&Bs[buf][0] + c * 4096 + f0);
        }
    };

    f32x4 acc[4][4];
    const f32x4 z4 = {0.f, 0.f, 0.f, 0.f};
    for (int a = 0; a < 4; ++a)
        for (int b2 = 0; b2 < 4; ++b2) acc[a][b2] = z4;

    const int nkt = (q0 + 128) / 64;   // causal: only k <= q0+127 contribute

    stage(0, 0);
    pipe_sync();
    for (int T = 0; T < nkt; ++T) {
        const int cur = T & 1;
        if (T + 1 < nkt) stage(cur ^ 1, (T + 1) * 64);
#pragma unroll
        for (int ks = 0; ks < 2; ++ks) {
            const int colb = ks * 64 + g * 16;
            short8 a_frag[4], b_frag[4];
#pragma unroll
            for (int mf = 0; mf < 4; ++mf)
                a_frag[mf] = *(const short8*)((const char*)&As[cur][0]
                                              + swz((wr * 64 + mf * 16 + l15) * 128 + colb));
#pragma unroll
            for (int nf = 0; nf < 4; ++nf)
                b_frag[nf] = *(const short8*)((const char*)&Bs[cur][0]
                                              + swz((wc * 64 + nf * 16 + l15) * 128 + colb));
            __builtin_amdgcn_s_setprio(1);
#pragma unroll
            for (int mf = 0; mf < 4; ++mf)
#pragma unroll
                for (int nf = 0; nf < 4; ++nf)
                    acc[mf][nf] = __builtin_amdgcn_mfma_f32_16x16x32_bf16(
                        a_frag[mf], b_frag[nf], acc[mf][nf], 0, 0, 0);
            __builtin_amdgcn_s_setprio(0);
        }
        pipe_sync();
    }

#pragma unroll
    for (int mf = 0; mf < 4; ++mf) {
#pragma unroll
        for (int nf = 0; nf < 4; ++nf) {
            int gq = q0 + wr * 64 + mf * 16 + 4 * g;
            int gn = n0 + wc * 64 + nf * 16 + l15;
#pragma unroll
            for (int i = 0; i < 4; ++i)
                seq[(size_t)(b * S_ + gq + i) * D_ + gn] = acc[mf][nf][i];
        }
    }
}

// ---------------------------------------------------------------- launch ----
extern "C" void kernel_launch(void* const* d_in, const int* in_sizes, int n_in,
                              void* d_out, int out_size, void* d_ws, size_t ws_size,
                              hipStream_t stream) {
    const float* q = (const float*)d_in[0];
    const float* k = (const float*)d_in[1];
    const float* v = (const float*)d_in[2];
    const unsigned char* pm = (const unsigned char*)d_in[3];
    const float* Wq = (const float*)d_in[5];
    const float* bq = (const float*)d_in[6];
    const float* Wk = (const float*)d_in[7];
    const float* bk = (const float*)d_in[8];
    const float* Wv = (const float*)d_in[9];
    const float* bv = (const float*)d_in[10];

    float* seq = (float*)d_out;
    float* attn = seq + (size_t)B_ * S_ * D_;

    char* ws = (char*)d_ws;
    int* lens = (int*)ws;
    unsigned short* Qb = (unsigned short*)(ws + 256);
    unsigned short* Kb = Qb + (size_t)B_ * S_ * D_;
    unsigned short* Vt = Kb + (size_t)B_ * S_ * D_;
    unsigned short* Xb = Vt + (size_t)B_ * D_ * S_;   // 3x B*S*D
    unsigned short* Wb = Xb + 3ull * B_ * S_ * D_;    // 3x D*D
    unsigned short* P = Qb;   // reuse Q+K region (exactly B*S*S bf16) after scores

    const size_t need = 256 + 6ull * B_ * S_ * D_ * 2 + 3ull * D_ * D_ * 2;

    lengths_kernel<<<1, 256, 0, stream>>>(pm, lens);

    if (ws_size >= need) {
        convert_all_kernel<<<dim3(B_ * S_ * D_ / 2048, 1, 6), 256, 0, stream>>>(
            q, k, v, Wq, Wk, Wv, Xb, Wb);
        proj2_kernel<<<dim3(3 * (B_ * S_ / 256) * (D_ / 256)), 512, 0, stream>>>(
            Xb, Wb, bq, bk, bv, Qb, Kb, Vt);
    } else {
        proj_kernel<<<dim3(D_ / 128, (B_ * S_) / 128, 3), 256, 0, stream>>>(
            q, k, v, Wq, Wk, Wv, bq, bk, bv, Qb, Kb, Vt);
    }

    scores_kernel<<<dim3(136 * B_), 256, 0, stream>>>(Qb, Kb, lens, attn);
    softmax_kernel<<<dim3(B_ * S_), 256, 0, stream>>>(lens, attn, P);
    pv_kernel<<<dim3(B_ * (S_ / 128) * (D_ / 128)), 256, 0, stream>>>(P, Vt, lens, seq);
}

// Round 13
// 440.141 us; speedup vs baseline: 3.4834x; 3.4834x over previous
//
#include <hip/hip_runtime.h>
#include <hip/hip_bf16.h>

#define B_ 8
#define S_ 2048
#define D_ 1024
#define SCALE 0.03125f   // 1/sqrt(1024)
#define NT_ (D_ / 64)    // K-tiles of 64

typedef __attribute__((ext_vector_type(4))) float f32x4;
typedef __attribute__((ext_vector_type(8))) short short8;
typedef __attribute__((ext_vector_type(4))) short short4v;

static __device__ inline unsigned short f2bf(float f) {
    unsigned int u = __float_as_uint(f);
    u += 0x7FFF + ((u >> 16) & 1);     // round-to-nearest-even
    return (unsigned short)(u >> 16);
}

static __device__ __forceinline__ void gload16(const void* g, void* l) {
    __builtin_amdgcn_global_load_lds(
        (const __attribute__((address_space(1))) unsigned int*)g,
        (__attribute__((address_space(3))) unsigned int*)l, 16, 0, 0);
}

static __device__ __forceinline__ void pipe_sync() {
    asm volatile("s_waitcnt vmcnt(0)" ::: "memory");
    __builtin_amdgcn_s_barrier();
    __builtin_amdgcn_sched_barrier(0);
}

// XCD-aware bijective swizzle (nwg divisible by 8).  [T1]
static __device__ __forceinline__ int xcd_swz(int hw, int nwg) {
    return (hw & 7) * (nwg >> 3) + (hw >> 3);
}

// Bank swizzle for [rows][64]bf16 (128B rows): XOR col-slot bits [6:4] with
// row&7 -> 16 same-col lanes land on 8 distinct 16B slots (2-way = free). [T2]
static __device__ __forceinline__ int swz(int byte) {
    return byte ^ (((byte >> 7) & 7) << 4);
}

// ---------------------------------------------------------------- lengths ---
__global__ void lengths_kernel(const unsigned char* __restrict__ pm, int* __restrict__ lens) {
    __shared__ int cnt[B_];
    int tid = threadIdx.x;
    if (tid < B_) cnt[tid] = 0;
    __syncthreads();
    int layout;
    if (pm[0] == 1 && pm[1] == 1) layout = 0;        // bool/uint8
    else if (pm[0] == 1) layout = 1;                 // int32
    else layout = 2;                                 // float32
    for (int i = tid; i < B_ * S_; i += blockDim.x) {
        bool v;
        if (layout == 0) v = pm[i] != 0;
        else if (layout == 1) v = ((const int*)pm)[i] != 0;
        else v = ((const float*)pm)[i] != 0.0f;
        if (v) atomicAdd(&cnt[i >> 11], 1);
    }
    __syncthreads();
    if (tid < B_) lens[tid] = cnt[tid];
}

// ---------------------------------------------------------------- convert ---
__global__ void convert_all_kernel(const float* __restrict__ q, const float* __restrict__ k,
                                   const float* __restrict__ v,
                                   const float* __restrict__ Wq, const float* __restrict__ Wk,
                                   const float* __restrict__ Wv,
                                   unsigned short* __restrict__ Xb,
                                   unsigned short* __restrict__ Wb) {
    const int z = blockIdx.z;
    const float* src;
    unsigned short* dst;
    int n;
    if (z < 3) {
        src = (z == 0) ? q : (z == 1) ? k : v;
        dst = Xb + (size_t)z * B_ * S_ * D_;
        n = B_ * S_ * D_;
    } else {
        src = (z == 3) ? Wq : (z == 4) ? Wk : Wv;
        dst = Wb + (size_t)(z - 3) * D_ * D_;
        n = D_ * D_;
    }
    int idx = (blockIdx.x * 256 + threadIdx.x) * 8;
    if (idx >= n) return;
    float4 a = *(const float4*)(src + idx);
    float4 b = *(const float4*)(src + idx + 4);
    short8 o;
    o[0] = (short)f2bf(a.x); o[1] = (short)f2bf(a.y);
    o[2] = (short)f2bf(a.z); o[3] = (short)f2bf(a.w);
    o[4] = (short)f2bf(b.x); o[5] = (short)f2bf(b.y);
    o[6] = (short)f2bf(b.z); o[7] = (short)f2bf(b.w);
    *(short8*)(dst + idx) = o;
}

// ---------------------------------------------------------------- proj 128^2
// scores-structure GEMM: 128x128 tile, 4 waves, BK=64 [128][64] swizzled LDS
// dbuf (64 KB -> 2 blocks/CU), depth-1 prefetch, 1 barrier per K-tile.
__global__ void proj128_kernel(const unsigned short* __restrict__ Xb3,
                               const unsigned short* __restrict__ Wb3,
                               const float* __restrict__ bq, const float* __restrict__ bk,
                               const float* __restrict__ bv,
                               unsigned short* __restrict__ Qb,
                               unsigned short* __restrict__ Kb,
                               unsigned short* __restrict__ Vt) {
    const int nwg = 3 * (B_ * S_ / 128) * (D_ / 128);   // 3072
    const int log_id = xcd_swz(blockIdx.x, nwg);
    const int z = log_id >> 10;                         // 1024 blocks per z
    const int rem = log_id & 1023;
    const int m0 = (rem >> 3) * 128;
    const int n0 = (rem & 7) * 128;                     // n fastest: A-panel share

    const unsigned short* Xb = Xb3 + (size_t)z * B_ * S_ * D_;
    const unsigned short* Wb = Wb3 + (size_t)z * D_ * D_;
    const float* bias = (z == 0) ? bq : (z == 1) ? bk : bv;

    __shared__ unsigned short As[2][128 * 64];   // 2 x 16 KB
    __shared__ unsigned short Bs[2][128 * 64];

    const int tid = threadIdx.x;
    const int lane = tid & 63, w = tid >> 6;
    const int wr = w >> 1, wc = w & 1;           // 2x2 waves, wave tile 64x64
    const int g = lane >> 4, l15 = lane & 15;

    const char* Abase_g = (const char*)(Xb + (size_t)m0 * D_);
    const char* Bbase_g = (const char*)(Wb + (size_t)n0 * D_);

    const int f0 = tid * 16;                 // 0..4080
    const int rs = f0 >> 7, cs = f0 & 127;   // rows 0..31
    const int csrc = cs ^ ((rs & 7) << 4);   // row&7 invariant under +32

    auto stage = [&](int buf, int kk) {
#pragma unroll
        for (int c = 0; c < 4; ++c) {
            gload16(Abase_g + (size_t)(rs + c * 32) * (D_ * 2) + kk * 2 + csrc,
                    (char*)&As[buf][0] + c * 4096 + f0);
            gload16(Bbase_g + (size_t)(rs + c * 32) * (D_ * 2) + kk * 2 + csrc,
                    (char*)&Bs[buf][0] + c * 4096 + f0);
        }
    };

    f32x4 acc[4][4];
    const f32x4 z4 = {0.f, 0.f, 0.f, 0.f};
    for (int a = 0; a < 4; ++a)
        for (int b2 = 0; b2 < 4; ++b2) acc[a][b2] = z4;

    stage(0, 0);
    pipe_sync();
    for (int T = 0; T < NT_; ++T) {
        const int cur = T & 1;
        if (T + 1 < NT_) stage(cur ^ 1, (T + 1) * 64);
#pragma unroll
        for (int ks = 0; ks < 2; ++ks) {
            const int colb = ks * 64 + g * 16;
            short8 a_frag[4], b_frag[4];
#pragma unroll
            for (int mf = 0; mf < 4; ++mf)
                a_frag[mf] = *(const short8*)((const char*)&As[cur][0]
                                              + swz((wr * 64 + mf * 16 + l15) * 128 + colb));
#pragma unroll
            for (int nf = 0; nf < 4; ++nf)
                b_frag[nf] = *(const short8*)((const char*)&Bs[cur][0]
                                              + swz((wc * 64 + nf * 16 + l15) * 128 + colb));
            __builtin_amdgcn_s_setprio(1);
#pragma unroll
            for (int mf = 0; mf < 4; ++mf)
#pragma unroll
                for (int nf = 0; nf < 4; ++nf)
                    acc[mf][nf] = __builtin_amdgcn_mfma_f32_16x16x32_bf16(
                        a_frag[mf], b_frag[nf], acc[mf][nf], 0, 0, 0);
            __builtin_amdgcn_s_setprio(0);
        }
        pipe_sync();
    }

    if (z < 2) {
        unsigned short* O = (z == 0) ? Qb : Kb;
#pragma unroll
        for (int mf = 0; mf < 4; ++mf) {
#pragma unroll
            for (int nf = 0; nf < 4; ++nf) {
                int gm = m0 + wr * 64 + mf * 16 + 4 * g;
                int gn = n0 + wc * 64 + nf * 16 + l15;
                float bb = bias[gn];
#pragma unroll
                for (int i = 0; i < 4; ++i)
                    O[(size_t)(gm + i) * D_ + gn] = f2bf(acc[mf][nf][i] + bb);
            }
        }
    } else {
#pragma unroll
        for (int mf = 0; mf < 4; ++mf) {
#pragma unroll
            for (int nf = 0; nf < 4; ++nf) {
                int gm = m0 + wr * 64 + mf * 16 + 4 * g;   // flat token
                int b = gm >> 11, tok = gm & 2047;
                int gn = n0 + wc * 64 + nf * 16 + l15;
                float bb = bias[gn];
                short4v sv;
#pragma unroll
                for (int i = 0; i < 4; ++i) sv[i] = (short)f2bf(acc[mf][nf][i] + bb);
                *(short4v*)(&Vt[((size_t)b * D_ + gn) * S_ + tok]) = sv;
            }
        }
    }
}

// ------------------------------------------------- proj (fused conv, fallback)
__global__ void proj_kernel(const float* __restrict__ q, const float* __restrict__ k,
                            const float* __restrict__ v,
                            const float* __restrict__ Wq, const float* __restrict__ Wk,
                            const float* __restrict__ Wv,
                            const float* __restrict__ bq, const float* __restrict__ bk,
                            const float* __restrict__ bv,
                            unsigned short* __restrict__ Qb, unsigned short* __restrict__ Kb,
                            unsigned short* __restrict__ Vt) {
    const int z = blockIdx.z;
    const float* X = (z == 0) ? q : (z == 1) ? k : v;
    const float* W = (z == 0) ? Wq : (z == 1) ? Wk : Wv;
    const float* bias = (z == 0) ? bq : (z == 1) ? bk : bv;

    __shared__ short As[128 * 40];
    __shared__ short Bs[128 * 40];

    const int m0 = blockIdx.y * 128;
    const int n0 = blockIdx.x * 128;
    const int tid = threadIdx.x;
    const int lane = tid & 63, wid = tid >> 6;
    const int wr = wid >> 1, wc = wid & 1;
    const int g = lane >> 4, l15 = lane & 15;

    f32x4 acc[4][4];
    const f32x4 z4 = {0.f, 0.f, 0.f, 0.f};
    for (int a = 0; a < 4; ++a)
        for (int b2 = 0; b2 < 4; ++b2) acc[a][b2] = z4;

    for (int kk = 0; kk < D_; kk += 32) {
#pragma unroll
        for (int it = 0; it < 4; ++it) {
            int flat = it * 1024 + tid * 4;
            int r = flat >> 5, c = flat & 31;
            float4 va = *(const float4*)(X + (size_t)(m0 + r) * D_ + kk + c);
            short4v sa = {(short)f2bf(va.x), (short)f2bf(va.y), (short)f2bf(va.z), (short)f2bf(va.w)};
            *(short4v*)(&As[r * 40 + c]) = sa;
            float4 vb = *(const float4*)(W + (size_t)(n0 + r) * D_ + kk + c);
            short4v sb = {(short)f2bf(vb.x), (short)f2bf(vb.y), (short)f2bf(vb.z), (short)f2bf(vb.w)};
            *(short4v*)(&Bs[r * 40 + c]) = sb;
        }
        __syncthreads();
        short8 a_frag[4], b_frag[4];
#pragma unroll
        for (int mf = 0; mf < 4; ++mf)
            a_frag[mf] = *(const short8*)(&As[(wr * 64 + mf * 16 + l15) * 40 + g * 8]);
#pragma unroll
        for (int nf = 0; nf < 4; ++nf)
            b_frag[nf] = *(const short8*)(&Bs[(wc * 64 + nf * 16 + l15) * 40 + g * 8]);
#pragma unroll
        for (int mf = 0; mf < 4; ++mf)
#pragma unroll
            for (int nf = 0; nf < 4; ++nf)
                acc[mf][nf] = __builtin_amdgcn_mfma_f32_16x16x32_bf16(a_frag[mf], b_frag[nf], acc[mf][nf], 0, 0, 0);
        __syncthreads();
    }

    if (z < 2) {
        unsigned short* O = (z == 0) ? Qb : Kb;
#pragma unroll
        for (int mf = 0; mf < 4; ++mf) {
#pragma unroll
            for (int nf = 0; nf < 4; ++nf) {
                int gm = m0 + wr * 64 + mf * 16 + 4 * g;
                int gn = n0 + wc * 64 + nf * 16 + l15;
                float bb = bias[gn];
#pragma unroll
                for (int i = 0; i < 4; ++i)
                    O[(size_t)(gm + i) * D_ + gn] = f2bf(acc[mf][nf][i] + bb);
            }
        }
    } else {
#pragma unroll
        for (int mf = 0; mf < 4; ++mf) {
#pragma unroll
            for (int nf = 0; nf < 4; ++nf) {
                int gm = m0 + wr * 64 + mf * 16 + 4 * g;
                int b = gm >> 11, tok = gm & 2047;
                int gn = n0 + wc * 64 + nf * 16 + l15;
                float bb = bias[gn];
                short4v sv;
#pragma unroll
                for (int i = 0; i < 4; ++i) sv[i] = (short)f2bf(acc[mf][nf][i] + bb);
                *(short4v*)(&Vt[((size_t)b * D_ + gn) * S_ + tok]) = sv;
            }
        }
    }
}

// ---------------------------------------------------------------- scores ----
// Causal-tiled GEMM, BK=64 [128][64] swizzled LDS, 1 barrier per K-tile.
__global__ void scores_kernel(const unsigned short* __restrict__ Qb,
                              const unsigned short* __restrict__ Kb,
                              const int* __restrict__ lens,
                              float* __restrict__ attn) {
    const int log_id = xcd_swz(blockIdx.x, 136 * B_);
    const int b = log_id / 136;
    const int idx = log_id - b * 136;
    int qt = (int)((sqrtf(8.f * idx + 1.f) - 1.f) * 0.5f);
    while ((qt + 1) * (qt + 2) / 2 <= idx) ++qt;
    while (qt * (qt + 1) / 2 > idx) --qt;
    const int kt = idx - qt * (qt + 1) / 2;
    const int m0 = qt * 128, n0 = kt * 128;
    const int len = lens[b];
    if (m0 >= len) return;

    __shared__ unsigned short As[2][128 * 64];   // 2 x 16 KB
    __shared__ unsigned short Bs[2][128 * 64];

    const int tid = threadIdx.x;
    const int lane = tid & 63, w = tid >> 6;
    const int wr = w >> 1, wc = w & 1;
    const int g = lane >> 4, l15 = lane & 15;

    const char* Qbase = (const char*)(Qb + (size_t)(b * S_ + m0) * D_);
    const char* Kbase = (const char*)(Kb + (size_t)(b * S_ + n0) * D_);

    const int f0 = tid * 16;                 // 0..4080
    const int rs = f0 >> 7, cs = f0 & 127;   // rows 0..31
    const int csrc = cs ^ ((rs & 7) << 4);   // row&7 invariant under +32

    auto stage = [&](int buf, int kk) {
#pragma unroll
        for (int c = 0; c < 4; ++c) {
            gload16(Qbase + (size_t)(rs + c * 32) * (D_ * 2) + kk * 2 + csrc,
                    (char*)&As[buf][0] + c * 4096 + f0);
            gload16(Kbase + (size_t)(rs + c * 32) * (D_ * 2) + kk * 2 + csrc,
                    (char*)&Bs[buf][0] + c * 4096 + f0);
        }
    };

    f32x4 acc[4][4];
    const f32x4 z4 = {0.f, 0.f, 0.f, 0.f};
    for (int a = 0; a < 4; ++a)
        for (int b2 = 0; b2 < 4; ++b2) acc[a][b2] = z4;

    stage(0, 0);
    pipe_sync();
    for (int T = 0; T < NT_; ++T) {
        const int cur = T & 1;
        if (T + 1 < NT_) stage(cur ^ 1, (T + 1) * 64);
#pragma unroll
        for (int ks = 0; ks < 2; ++ks) {
            const int colb = ks * 64 + g * 16;
            short8 a_frag[4], b_frag[4];
#pragma unroll
            for (int mf = 0; mf < 4; ++mf)
                a_frag[mf] = *(const short8*)((const char*)&As[cur][0]
                                              + swz((wr * 64 + mf * 16 + l15) * 128 + colb));
#pragma unroll
            for (int nf = 0; nf < 4; ++nf)
                b_frag[nf] = *(const short8*)((const char*)&Bs[cur][0]
                                              + swz((wc * 64 + nf * 16 + l15) * 128 + colb));
            __builtin_amdgcn_s_setprio(1);
#pragma unroll
            for (int mf = 0; mf < 4; ++mf)
#pragma unroll
                for (int nf = 0; nf < 4; ++nf)
                    acc[mf][nf] = __builtin_amdgcn_mfma_f32_16x16x32_bf16(
                        a_frag[mf], b_frag[nf], acc[mf][nf], 0, 0, 0);
            __builtin_amdgcn_s_setprio(0);
        }
        pipe_sync();
    }

    const bool interior = (m0 >= n0 + 128) && (m0 + 128 <= len);
    if (interior) {
#pragma unroll
        for (int mf = 0; mf < 4; ++mf) {
#pragma unroll
            for (int nf = 0; nf < 4; ++nf) {
                int gm = m0 + wr * 64 + mf * 16 + 4 * g;
                int gn = n0 + wc * 64 + nf * 16 + l15;
#pragma unroll
                for (int i = 0; i < 4; ++i)
                    attn[(size_t)(b * S_ + gm + i) * S_ + gn] = acc[mf][nf][i] * SCALE;
            }
        }
    } else {
#pragma unroll
        for (int mf = 0; mf < 4; ++mf) {
#pragma unroll
            for (int nf = 0; nf < 4; ++nf) {
                int gm = m0 + wr * 64 + mf * 16 + 4 * g;
                int gn = n0 + wc * 64 + nf * 16 + l15;
#pragma unroll
                for (int i = 0; i < 4; ++i) {
                    int rq = gm + i;
                    if (rq < len && gn <= rq)
                        attn[(size_t)(b * S_ + rq) * S_ + gn] = acc[mf][nf][i] * SCALE;
                }
            }
        }
    }
}

// ---------------------------------------------------------------- softmax ---
__global__ void softmax_kernel(const int* __restrict__ lens,
                               float* __restrict__ attn, unsigned short* __restrict__ P) {
    const int row = blockIdx.x;
    const int b = row >> 11, qpos = row & 2047;
    const int tid = threadIdx.x;
    const size_t rbase = (size_t)row * S_;
    const int c0 = tid * 8;
    const short8 zp = {0, 0, 0, 0, 0, 0, 0, 0};
    const float4 zf = {0.f, 0.f, 0.f, 0.f};
    if (qpos >= lens[b]) {
        *(short8*)(&P[rbase + c0]) = zp;
        *(float4*)(attn + rbase + c0) = zf;
        *(float4*)(attn + rbase + c0 + 4) = zf;
        return;
    }
    __shared__ float wm[4], wl[4];
    const bool act = (c0 <= qpos);
    float x[8];
    if (act) {
        float4 a0 = *(const float4*)(attn + rbase + c0);
        float4 a1 = *(const float4*)(attn + rbase + c0 + 4);
        x[0] = a0.x; x[1] = a0.y; x[2] = a0.z; x[3] = a0.w;
        x[4] = a1.x; x[5] = a1.y; x[6] = a1.z; x[7] = a1.w;
#pragma unroll
        for (int j = 0; j < 8; ++j)
            if (c0 + j > qpos) x[j] = -1e30f;
    } else {
#pragma unroll
        for (int j = 0; j < 8; ++j) x[j] = -1e30f;
    }
    float lmax = -1e30f;
#pragma unroll
    for (int j = 0; j < 8; ++j) lmax = fmaxf(lmax, x[j]);
#pragma unroll
    for (int off = 1; off < 64; off <<= 1) lmax = fmaxf(lmax, __shfl_xor(lmax, off));
    if ((tid & 63) == 0) wm[tid >> 6] = lmax;
    __syncthreads();
    const float m = fmaxf(fmaxf(wm[0], wm[1]), fmaxf(wm[2], wm[3]));
    float e[8];
    float lsum = 0.f;
#pragma unroll
    for (int j = 0; j < 8; ++j) {
        e[j] = (x[j] > -1e29f) ? __expf(x[j] - m) : 0.f;
        lsum += e[j];
    }
#pragma unroll
    for (int off = 1; off < 64; off <<= 1) lsum += __shfl_xor(lsum, off);
    if ((tid & 63) == 0) wl[tid >> 6] = lsum;
    __syncthreads();
    if (act) {
        const float inv = 1.0f / (wl[0] + wl[1] + wl[2] + wl[3]);
        float4 o0, o1;
        short8 pb;
#pragma unroll
        for (int j = 0; j < 8; ++j) {
            e[j] *= inv;
            pb[j] = (short)f2bf(e[j]);
        }
        o0.x = e[0]; o0.y = e[1]; o0.z = e[2]; o0.w = e[3];
        o1.x = e[4]; o1.y = e[5]; o1.z = e[6]; o1.w = e[7];
        *(float4*)(attn + rbase + c0) = o0;
        *(float4*)(attn + rbase + c0 + 4) = o1;
        *(short8*)(&P[rbase + c0]) = pb;
    } else {
        *(float4*)(attn + rbase + c0) = zf;
        *(float4*)(attn + rbase + c0 + 4) = zf;
        *(short8*)(&P[rbase + c0]) = zp;
    }
}

// ---------------------------------------------------------------- PV --------
// BK=64 [128][64] swizzled LDS, 1 barrier per K-tile.
__global__ void pv_kernel(const unsigned short* __restrict__ P,
                          const unsigned short* __restrict__ Vt,
                          const int* __restrict__ lens, float* __restrict__ seq) {
    const int log_id = xcd_swz(blockIdx.x, B_ * (S_ / 128) * (D_ / 128));
    const int b = log_id >> 7;
    const int rem = log_id & 127;
    const int q0 = (rem >> 3) * 128;
    const int n0 = (rem & 7) * 128;
    const int len = lens[b];
    const int tid = threadIdx.x;

    if (q0 >= len) {
        const float4 zf = {0.f, 0.f, 0.f, 0.f};
#pragma unroll
        for (int it = 0; it < 16; ++it) {
            int flat = it * 1024 + tid * 4;
            int r = flat >> 7, c = flat & 127;
            *(float4*)(&seq[(size_t)(b * S_ + q0 + r) * D_ + n0 + c]) = zf;
        }
        return;
    }

    __shared__ unsigned short As[2][128 * 64];
    __shared__ unsigned short Bs[2][128 * 64];
    const int lane = tid & 63, w = tid >> 6;
    const int wr = w >> 1, wc = w & 1;
    const int g = lane >> 4, l15 = lane & 15;

    const char* Pbase = (const char*)(P + (size_t)(b * S_ + q0) * S_);
    const char* Vbase = (const char*)(Vt + ((size_t)b * D_ + n0) * S_);

    const int f0 = tid * 16;
    const int rs = f0 >> 7, cs = f0 & 127;
    const int csrc = cs ^ ((rs & 7) << 4);

    auto stage = [&](int buf, int kk) {
#pragma unroll
        for (int c = 0; c < 4; ++c) {
            gload16(Pbase + (size_t)(rs + c * 32) * (S_ * 2) + kk * 2 + csrc,
                    (char*)&As[buf][0] + c * 4096 + f0);
            gload16(Vbase + (size_t)(rs + c * 32) * (S_ * 2) + kk * 2 + csrc,
                    (char*)&Bs[buf][0] + c * 4096 + f0);
        }
    };

    f32x4 acc[4][4];
    const f32x4 z4 = {0.f, 0.f, 0.f, 0.f};
    for (int a = 0; a < 4; ++a)
        for (int b2 = 0; b2 < 4; ++b2) acc[a][b2] = z4;

    const int nkt = (q0 + 128) / 64;   // causal: only k <= q0+127 contribute

    stage(0, 0);
    pipe_sync();
    for (int T = 0; T < nkt; ++T) {
        const int cur = T & 1;
        if (T + 1 < nkt) stage(cur ^ 1, (T + 1) * 64);
#pragma unroll
        for (int ks = 0; ks < 2; ++ks) {
            const int colb = ks * 64 + g * 16;
            short8 a_frag[4], b_frag[4];
#pragma unroll
            for (int mf = 0; mf < 4; ++mf)
                a_frag[mf] = *(const short8*)((const char*)&As[cur][0]
                                              + swz((wr * 64 + mf * 16 + l15) * 128 + colb));
#pragma unroll
            for (int nf = 0; nf < 4; ++nf)
                b_frag[nf] = *(const short8*)((const char*)&Bs[cur][0]
                                              + swz((wc * 64 + nf * 16 + l15) * 128 + colb));
            __builtin_amdgcn_s_setprio(1);
#pragma unroll
            for (int mf = 0; mf < 4; ++mf)
#pragma unroll
                for (int nf = 0; nf < 4; ++nf)
                    acc[mf][nf] = __builtin_amdgcn_mfma_f32_16x16x32_bf16(
                        a_frag[mf], b_frag[nf], acc[mf][nf], 0, 0, 0);
            __builtin_amdgcn_s_setprio(0);
        }
        pipe_sync();
    }

#pragma unroll
    for (int mf = 0; mf < 4; ++mf) {
#pragma unroll
        for (int nf = 0; nf < 4; ++nf) {
            int gq = q0 + wr * 64 + mf * 16 + 4 * g;
            int gn = n0 + wc * 64 + nf * 16 + l15;
#pragma unroll
            for (int i = 0; i < 4; ++i)
                seq[(size_t)(b * S_ + gq + i) * D_ + gn] = acc[mf][nf][i];
        }
    }
}

// ---------------------------------------------------------------- launch ----
extern "C" void kernel_launch(void* const* d_in, const int* in_sizes, int n_in,
                              void* d_out, int out_size, void* d_ws, size_t ws_size,
                              hipStream_t stream) {
    const float* q = (const float*)d_in[0];
    const float* k = (const float*)d_in[1];
    const float* v = (const float*)d_in[2];
    const unsigned char* pm = (const unsigned char*)d_in[3];
    const float* Wq = (const float*)d_in[5];
    const float* bq = (const float*)d_in[6];
    const float* Wk = (const float*)d_in[7];
    const float* bk = (const float*)d_in[8];
    const float* Wv = (const float*)d_in[9];
    const float* bv = (const float*)d_in[10];

    float* seq = (float*)d_out;
    float* attn = seq + (size_t)B_ * S_ * D_;

    char* ws = (char*)d_ws;
    int* lens = (int*)ws;
    unsigned short* Qb = (unsigned short*)(ws + 256);
    unsigned short* Kb = Qb + (size_t)B_ * S_ * D_;
    unsigned short* Vt = Kb + (size_t)B_ * S_ * D_;
    unsigned short* Xb = Vt + (size_t)B_ * D_ * S_;   // 3x B*S*D
    unsigned short* Wb = Xb + 3ull * B_ * S_ * D_;    // 3x D*D
    unsigned short* P = Qb;   // reuse Q+K region (exactly B*S*S bf16) after scores

    const size_t need = 256 + 6ull * B_ * S_ * D_ * 2 + 3ull * D_ * D_ * 2;

    lengths_kernel<<<1, 256, 0, stream>>>(pm, lens);

    if (ws_size >= need) {
        convert_all_kernel<<<dim3(B_ * S_ * D_ / 2048, 1, 6), 256, 0, stream>>>(
            q, k, v, Wq, Wk, Wv, Xb, Wb);
        proj128_kernel<<<dim3(3 * (B_ * S_ / 128) * (D_ / 128)), 256, 0, stream>>>(
            Xb, Wb, bq, bk, bv, Qb, Kb, Vt);
    } else {
        proj_kernel<<<dim3(D_ / 128, (B_ * S_) / 128, 3), 256, 0, stream>>>(
            q, k, v, Wq, Wk, Wv, bq, bk, bv, Qb, Kb, Vt);
    }

    scores_kernel<<<dim3(136 * B_), 256, 0, stream>>>(Qb, Kb, lens, attn);
    softmax_kernel<<<dim3(B_ * S_), 256, 0, stream>>>(lens, attn, P);
    pv_kernel<<<dim3(B_ * (S_ / 128) * (D_ / 128)), 256, 0, stream>>>(P, Vt, lens, seq);
}

// Round 14
// 384.823 us; speedup vs baseline: 3.9842x; 1.1437x over previous
//
#include <hip/hip_runtime.h>
#include <hip/hip_bf16.h>

#define B_ 8
#define S_ 2048
#define D_ 1024
#define SCALE 0.03125f   // 1/sqrt(1024)
#define NT_ (D_ / 64)    // K-tiles of 64

typedef __attribute__((ext_vector_type(4))) float f32x4;
typedef __attribute__((ext_vector_type(8))) short short8;
typedef __attribute__((ext_vector_type(4))) short short4v;

static __device__ inline unsigned short f2bf(float f) {
    unsigned int u = __float_as_uint(f);
    u += 0x7FFF + ((u >> 16) & 1);     // round-to-nearest-even
    return (unsigned short)(u >> 16);
}

static __device__ __forceinline__ void gload16(const void* g, void* l) {
    __builtin_amdgcn_global_load_lds(
        (const __attribute__((address_space(1))) unsigned int*)g,
        (__attribute__((address_space(3))) unsigned int*)l, 16, 0, 0);
}

static __device__ __forceinline__ void pipe_sync() {
    asm volatile("s_waitcnt vmcnt(0)" ::: "memory");
    __builtin_amdgcn_s_barrier();
    __builtin_amdgcn_sched_barrier(0);
}

// XCD-aware bijective swizzle (nwg divisible by 8).  [T1]
static __device__ __forceinline__ int xcd_swz(int hw, int nwg) {
    return (hw & 7) * (nwg >> 3) + (hw >> 3);
}

// Bank swizzle for [rows][64]bf16 (128B rows): XOR col-slot bits [6:4] with
// row&7 -> 16 same-col lanes land on 8 distinct 16B slots (2-way = free). [T2]
static __device__ __forceinline__ int swz(int byte) {
    return byte ^ (((byte >> 7) & 7) << 4);
}

// ---------------------------------------------------------------- lengths ---
__global__ void lengths_kernel(const unsigned char* __restrict__ pm, int* __restrict__ lens) {
    __shared__ int cnt[B_];
    int tid = threadIdx.x;
    if (tid < B_) cnt[tid] = 0;
    __syncthreads();
    int layout;
    if (pm[0] == 1 && pm[1] == 1) layout = 0;        // bool/uint8
    else if (pm[0] == 1) layout = 1;                 // int32
    else layout = 2;                                 // float32
    for (int i = tid; i < B_ * S_; i += blockDim.x) {
        bool v;
        if (layout == 0) v = pm[i] != 0;
        else if (layout == 1) v = ((const int*)pm)[i] != 0;
        else v = ((const float*)pm)[i] != 0.0f;
        if (v) atomicAdd(&cnt[i >> 11], 1);
    }
    __syncthreads();
    if (tid < B_) lens[tid] = cnt[tid];
}

// ---------------------------------------------------------------- convert ---
__global__ void convert_all_kernel(const float* __restrict__ q, const float* __restrict__ k,
                                   const float* __restrict__ v,
                                   const float* __restrict__ Wq, const float* __restrict__ Wk,
                                   const float* __restrict__ Wv,
                                   unsigned short* __restrict__ Xb,
                                   unsigned short* __restrict__ Wb) {
    const int z = blockIdx.z;
    const float* src;
    unsigned short* dst;
    int n;
    if (z < 3) {
        src = (z == 0) ? q : (z == 1) ? k : v;
        dst = Xb + (size_t)z * B_ * S_ * D_;
        n = B_ * S_ * D_;
    } else {
        src = (z == 3) ? Wq : (z == 4) ? Wk : Wv;
        dst = Wb + (size_t)(z - 3) * D_ * D_;
        n = D_ * D_;
    }
    int idx = (blockIdx.x * 256 + threadIdx.x) * 8;
    if (idx >= n) return;
    float4 a = *(const float4*)(src + idx);
    float4 b = *(const float4*)(src + idx + 4);
    short8 o;
    o[0] = (short)f2bf(a.x); o[1] = (short)f2bf(a.y);
    o[2] = (short)f2bf(a.z); o[3] = (short)f2bf(a.w);
    o[4] = (short)f2bf(b.x); o[5] = (short)f2bf(b.y);
    o[6] = (short)f2bf(b.z); o[7] = (short)f2bf(b.w);
    *(short8*)(dst + idx) = o;
}

// ---------------------------------------------------------------- proj 256^2
// 8-wave 256x256, BK=64, 128KB LDS dbuf, swizzled; straight-line tile compute
// (compiler interleaves ds_read/MFMA); 2 barriers per K-tile at boundary only.
__global__ __launch_bounds__(512, 1) void proj2_kernel(
        const unsigned short* __restrict__ Xb3,
        const unsigned short* __restrict__ Wb3,
        const float* __restrict__ bq, const float* __restrict__ bk,
        const float* __restrict__ bv,
        unsigned short* __restrict__ Qb,
        unsigned short* __restrict__ Kb,
        unsigned short* __restrict__ Vt) {
    const int nwg = 3 * (B_ * S_ / 256) * (D_ / 256);   // 768
    const int log_id = xcd_swz(blockIdx.x, nwg);
    const int z = log_id >> 8;                          // 256 blocks per z
    const int rem = log_id & 255;
    const int m0 = (rem >> 2) * 256;
    const int n0 = (rem & 3) * 256;

    const unsigned short* Xb = Xb3 + (size_t)z * B_ * S_ * D_;
    const unsigned short* Wb = Wb3 + (size_t)z * D_ * D_;
    const float* bias = (z == 0) ? bq : (z == 1) ? bk : bv;

    // [buf][A=0/B=1][half][128*64] bf16 = 128 KB
    __shared__ unsigned short lds[2][2][2][128 * 64];

    const int tid = threadIdx.x;
    const int lane = tid & 63, wid = tid >> 6;
    const int wm = wid >> 2, wn = wid & 3;       // 2M x 4N waves; wave tile 128x64
    const int g = lane >> 4, l15 = lane & 15;

    // staging: linear LDS dest (rule #21); GLOBAL source column pre-swizzled.
    const int f0 = tid * 16;
    const int r0s = f0 >> 7, c0s = f0 & 127;
    const int csrc = c0s ^ ((r0s & 7) << 4);   // row&7 invariant under +64

    f32x4 acc[8][4];
    const f32x4 z4 = {0.f, 0.f, 0.f, 0.f};
#pragma unroll
    for (int a = 0; a < 8; ++a)
#pragma unroll
        for (int b2 = 0; b2 < 4; ++b2) acc[a][b2] = z4;

    auto stageT = [&](int buf, int kk) {
#pragma unroll
        for (int h = 0; h < 2; ++h) {
            gload16((const char*)Xb + ((size_t)(m0 + h * 128 + r0s) * D_ + kk) * 2 + csrc,
                    (char*)&lds[buf][0][h][0] + f0);
            gload16((const char*)Xb + ((size_t)(m0 + h * 128 + r0s + 64) * D_ + kk) * 2 + csrc,
                    (char*)&lds[buf][0][h][0] + f0 + 8192);
            gload16((const char*)Wb + ((size_t)(n0 + h * 128 + r0s) * D_ + kk) * 2 + csrc,
                    (char*)&lds[buf][1][h][0] + f0);
            gload16((const char*)Wb + ((size_t)(n0 + h * 128 + r0s + 64) * D_ + kk) * 2 + csrc,
                    (char*)&lds[buf][1][h][0] + f0 + 8192);
        }
    };

    stageT(0, 0);
    pipe_sync();

    for (int T = 0; T < NT_; ++T) {
        const int buf = T & 1;
        if (T + 1 < NT_) stageT(buf ^ 1, (T + 1) * 64);
        const char* Abase = (const char*)&lds[buf][0][wm][0];
#pragma unroll
        for (int ks = 0; ks < 2; ++ks) {
            const int colb = ks * 64 + g * 16;
            short8 bfr[4], afr[8];
#pragma unroll
            for (int nf = 0; nf < 4; ++nf) {
                int nl = wn * 64 + nf * 16 + l15;
                bfr[nf] = *(const short8*)((const char*)&lds[buf][1][nl >> 7][0]
                                           + swz((nl & 127) * 128 + colb));
            }
#pragma unroll
            for (int mf = 0; mf < 8; ++mf)
                afr[mf] = *(const short8*)(Abase + swz((mf * 16 + l15) * 128 + colb));
            __builtin_amdgcn_s_setprio(1);
#pragma unroll
            for (int mf = 0; mf < 8; ++mf)
#pragma unroll
                for (int nf = 0; nf < 4; ++nf)
                    acc[mf][nf] = __builtin_amdgcn_mfma_f32_16x16x32_bf16(
                        afr[mf], bfr[nf], acc[mf][nf], 0, 0, 0);
            __builtin_amdgcn_s_setprio(0);
        }
        pipe_sync();
    }

    if (z < 2) {
        unsigned short* O = (z == 0) ? Qb : Kb;
#pragma unroll
        for (int mf = 0; mf < 8; ++mf) {
#pragma unroll
            for (int nf = 0; nf < 4; ++nf) {
                int gm = m0 + wm * 128 + mf * 16 + 4 * g;
                int gn = n0 + wn * 64 + nf * 16 + l15;
                float bb = bias[gn];
#pragma unroll
                for (int i = 0; i < 4; ++i)
                    O[(size_t)(gm + i) * D_ + gn] = f2bf(acc[mf][nf][i] + bb);
            }
        }
    } else {
#pragma unroll
        for (int mf = 0; mf < 8; ++mf) {
#pragma unroll
            for (int nf = 0; nf < 4; ++nf) {
                int gm = m0 + wm * 128 + mf * 16 + 4 * g;   // flat token
                int b = gm >> 11, tok = gm & 2047;
                int gn = n0 + wn * 64 + nf * 16 + l15;
                float bb = bias[gn];
                short4v sv;
#pragma unroll
                for (int i = 0; i < 4; ++i) sv[i] = (short)f2bf(acc[mf][nf][i] + bb);
                *(short4v*)(&Vt[((size_t)b * D_ + gn) * S_ + tok]) = sv;
            }
        }
    }
}

// ------------------------------------------------- proj (fused conv, fallback)
__global__ void proj_kernel(const float* __restrict__ q, const float* __restrict__ k,
                            const float* __restrict__ v,
                            const float* __restrict__ Wq, const float* __restrict__ Wk,
                            const float* __restrict__ Wv,
                            const float* __restrict__ bq, const float* __restrict__ bk,
                            const float* __restrict__ bv,
                            unsigned short* __restrict__ Qb, unsigned short* __restrict__ Kb,
                            unsigned short* __restrict__ Vt) {
    const int z = blockIdx.z;
    const float* X = (z == 0) ? q : (z == 1) ? k : v;
    const float* W = (z == 0) ? Wq : (z == 1) ? Wk : Wv;
    const float* bias = (z == 0) ? bq : (z == 1) ? bk : bv;

    __shared__ short As[128 * 40];
    __shared__ short Bs[128 * 40];

    const int m0 = blockIdx.y * 128;
    const int n0 = blockIdx.x * 128;
    const int tid = threadIdx.x;
    const int lane = tid & 63, wid = tid >> 6;
    const int wr = wid >> 1, wc = wid & 1;
    const int g = lane >> 4, l15 = lane & 15;

    f32x4 acc[4][4];
    const f32x4 z4 = {0.f, 0.f, 0.f, 0.f};
    for (int a = 0; a < 4; ++a)
        for (int b2 = 0; b2 < 4; ++b2) acc[a][b2] = z4;

    for (int kk = 0; kk < D_; kk += 32) {
#pragma unroll
        for (int it = 0; it < 4; ++it) {
            int flat = it * 1024 + tid * 4;
            int r = flat >> 5, c = flat & 31;
            float4 va = *(const float4*)(X + (size_t)(m0 + r) * D_ + kk + c);
            short4v sa = {(short)f2bf(va.x), (short)f2bf(va.y), (short)f2bf(va.z), (short)f2bf(va.w)};
            *(short4v*)(&As[r * 40 + c]) = sa;
            float4 vb = *(const float4*)(W + (size_t)(n0 + r) * D_ + kk + c);
            short4v sb = {(short)f2bf(vb.x), (short)f2bf(vb.y), (short)f2bf(vb.z), (short)f2bf(vb.w)};
            *(short4v*)(&Bs[r * 40 + c]) = sb;
        }
        __syncthreads();
        short8 a_frag[4], b_frag[4];
#pragma unroll
        for (int mf = 0; mf < 4; ++mf)
            a_frag[mf] = *(const short8*)(&As[(wr * 64 + mf * 16 + l15) * 40 + g * 8]);
#pragma unroll
        for (int nf = 0; nf < 4; ++nf)
            b_frag[nf] = *(const short8*)(&Bs[(wc * 64 + nf * 16 + l15) * 40 + g * 8]);
#pragma unroll
        for (int mf = 0; mf < 4; ++mf)
#pragma unroll
            for (int nf = 0; nf < 4; ++nf)
                acc[mf][nf] = __builtin_amdgcn_mfma_f32_16x16x32_bf16(a_frag[mf], b_frag[nf], acc[mf][nf], 0, 0, 0);
        __syncthreads();
    }

    if (z < 2) {
        unsigned short* O = (z == 0) ? Qb : Kb;
#pragma unroll
        for (int mf = 0; mf < 4; ++mf) {
#pragma unroll
            for (int nf = 0; nf < 4; ++nf) {
                int gm = m0 + wr * 64 + mf * 16 + 4 * g;
                int gn = n0 + wc * 64 + nf * 16 + l15;
                float bb = bias[gn];
#pragma unroll
                for (int i = 0; i < 4; ++i)
                    O[(size_t)(gm + i) * D_ + gn] = f2bf(acc[mf][nf][i] + bb);
            }
        }
    } else {
#pragma unroll
        for (int mf = 0; mf < 4; ++mf) {
#pragma unroll
            for (int nf = 0; nf < 4; ++nf) {
                int gm = m0 + wr * 64 + mf * 16 + 4 * g;
                int b = gm >> 11, tok = gm & 2047;
                int gn = n0 + wc * 64 + nf * 16 + l15;
                float bb = bias[gn];
                short4v sv;
#pragma unroll
                for (int i = 0; i < 4; ++i) sv[i] = (short)f2bf(acc[mf][nf][i] + bb);
                *(short4v*)(&Vt[((size_t)b * D_ + gn) * S_ + tok]) = sv;
            }
        }
    }
}

// ---------------------------------------------------------------- scores ----
// Causal-tiled GEMM, BK=64 [128][64] swizzled LDS, 1 barrier per K-tile.
__global__ void scores_kernel(const unsigned short* __restrict__ Qb,
                              const unsigned short* __restrict__ Kb,
                              const int* __restrict__ lens,
                              float* __restrict__ attn) {
    const int log_id = xcd_swz(blockIdx.x, 136 * B_);
    const int b = log_id / 136;
    const int idx = log_id - b * 136;
    int qt = (int)((sqrtf(8.f * idx + 1.f) - 1.f) * 0.5f);
    while ((qt + 1) * (qt + 2) / 2 <= idx) ++qt;
    while (qt * (qt + 1) / 2 > idx) --qt;
    const int kt = idx - qt * (qt + 1) / 2;
    const int m0 = qt * 128, n0 = kt * 128;
    const int len = lens[b];
    if (m0 >= len) return;

    __shared__ unsigned short As[2][128 * 64];   // 2 x 16 KB
    __shared__ unsigned short Bs[2][128 * 64];

    const int tid = threadIdx.x;
    const int lane = tid & 63, w = tid >> 6;
    const int wr = w >> 1, wc = w & 1;
    const int g = lane >> 4, l15 = lane & 15;

    const char* Qbase = (const char*)(Qb + (size_t)(b * S_ + m0) * D_);
    const char* Kbase = (const char*)(Kb + (size_t)(b * S_ + n0) * D_);

    const int f0 = tid * 16;                 // 0..4080
    const int rs = f0 >> 7, cs = f0 & 127;   // rows 0..31
    const int csrc = cs ^ ((rs & 7) << 4);   // row&7 invariant under +32

    auto stage = [&](int buf, int kk) {
#pragma unroll
        for (int c = 0; c < 4; ++c) {
            gload16(Qbase + (size_t)(rs + c * 32) * (D_ * 2) + kk * 2 + csrc,
                    (char*)&As[buf][0] + c * 4096 + f0);
            gload16(Kbase + (size_t)(rs + c * 32) * (D_ * 2) + kk * 2 + csrc,
                    (char*)&Bs[buf][0] + c * 4096 + f0);
        }
    };

    f32x4 acc[4][4];
    const f32x4 z4 = {0.f, 0.f, 0.f, 0.f};
    for (int a = 0; a < 4; ++a)
        for (int b2 = 0; b2 < 4; ++b2) acc[a][b2] = z4;

    stage(0, 0);
    pipe_sync();
    for (int T = 0; T < NT_; ++T) {
        const int cur = T & 1;
        if (T + 1 < NT_) stage(cur ^ 1, (T + 1) * 64);
#pragma unroll
        for (int ks = 0; ks < 2; ++ks) {
            const int colb = ks * 64 + g * 16;
            short8 a_frag[4], b_frag[4];
#pragma unroll
            for (int mf = 0; mf < 4; ++mf)
                a_frag[mf] = *(const short8*)((const char*)&As[cur][0]
                                              + swz((wr * 64 + mf * 16 + l15) * 128 + colb));
#pragma unroll
            for (int nf = 0; nf < 4; ++nf)
                b_frag[nf] = *(const short8*)((const char*)&Bs[cur][0]
                                              + swz((wc * 64 + nf * 16 + l15) * 128 + colb));
            __builtin_amdgcn_s_setprio(1);
#pragma unroll
            for (int mf = 0; mf < 4; ++mf)
#pragma unroll
                for (int nf = 0; nf < 4; ++nf)
                    acc[mf][nf] = __builtin_amdgcn_mfma_f32_16x16x32_bf16(
                        a_frag[mf], b_frag[nf], acc[mf][nf], 0, 0, 0);
            __builtin_amdgcn_s_setprio(0);
        }
        pipe_sync();
    }

    const bool interior = (m0 >= n0 + 128) && (m0 + 128 <= len);
    if (interior) {
#pragma unroll
        for (int mf = 0; mf < 4; ++mf) {
#pragma unroll
            for (int nf = 0; nf < 4; ++nf) {
                int gm = m0 + wr * 64 + mf * 16 + 4 * g;
                int gn = n0 + wc * 64 + nf * 16 + l15;
#pragma unroll
                for (int i = 0; i < 4; ++i)
                    attn[(size_t)(b * S_ + gm + i) * S_ + gn] = acc[mf][nf][i] * SCALE;
            }
        }
    } else {
#pragma unroll
        for (int mf = 0; mf < 4; ++mf) {
#pragma unroll
            for (int nf = 0; nf < 4; ++nf) {
                int gm = m0 + wr * 64 + mf * 16 + 4 * g;
                int gn = n0 + wc * 64 + nf * 16 + l15;
#pragma unroll
                for (int i = 0; i < 4; ++i) {
                    int rq = gm + i;
                    if (rq < len && gn <= rq)
                        attn[(size_t)(b * S_ + rq) * S_ + gn] = acc[mf][nf][i] * SCALE;
                }
            }
        }
    }
}

// ---------------------------------------------------------------- softmax ---
__global__ void softmax_kernel(const int* __restrict__ lens,
                               float* __restrict__ attn, unsigned short* __restrict__ P) {
    const int row = blockIdx.x;
    const int b = row >> 11, qpos = row & 2047;
    const int tid = threadIdx.x;
    const size_t rbase = (size_t)row * S_;
    const int c0 = tid * 8;
    const short8 zp = {0, 0, 0, 0, 0, 0, 0, 0};
    const float4 zf = {0.f, 0.f, 0.f, 0.f};
    if (qpos >= lens[b]) {
        *(short8*)(&P[rbase + c0]) = zp;
        *(float4*)(attn + rbase + c0) = zf;
        *(float4*)(attn + rbase + c0 + 4) = zf;
        return;
    }
    __shared__ float wm[4], wl[4];
    const bool act = (c0 <= qpos);
    float x[8];
    if (act) {
        float4 a0 = *(const float4*)(attn + rbase + c0);
        float4 a1 = *(const float4*)(attn + rbase + c0 + 4);
        x[0] = a0.x; x[1] = a0.y; x[2] = a0.z; x[3] = a0.w;
        x[4] = a1.x; x[5] = a1.y; x[6] = a1.z; x[7] = a1.w;
#pragma unroll
        for (int j = 0; j < 8; ++j)
            if (c0 + j > qpos) x[j] = -1e30f;
    } else {
#pragma unroll
        for (int j = 0; j < 8; ++j) x[j] = -1e30f;
    }
    float lmax = -1e30f;
#pragma unroll
    for (int j = 0; j < 8; ++j) lmax = fmaxf(lmax, x[j]);
#pragma unroll
    for (int off = 1; off < 64; off <<= 1) lmax = fmaxf(lmax, __shfl_xor(lmax, off));
    if ((tid & 63) == 0) wm[tid >> 6] = lmax;
    __syncthreads();
    const float m = fmaxf(fmaxf(wm[0], wm[1]), fmaxf(wm[2], wm[3]));
    float e[8];
    float lsum = 0.f;
#pragma unroll
    for (int j = 0; j < 8; ++j) {
        e[j] = (x[j] > -1e29f) ? __expf(x[j] - m) : 0.f;
        lsum += e[j];
    }
#pragma unroll
    for (int off = 1; off < 64; off <<= 1) lsum += __shfl_xor(lsum, off);
    if ((tid & 63) == 0) wl[tid >> 6] = lsum;
    __syncthreads();
    if (act) {
        const float inv = 1.0f / (wl[0] + wl[1] + wl[2] + wl[3]);
        float4 o0, o1;
        short8 pb;
#pragma unroll
        for (int j = 0; j < 8; ++j) {
            e[j] *= inv;
            pb[j] = (short)f2bf(e[j]);
        }
        o0.x = e[0]; o0.y = e[1]; o0.z = e[2]; o0.w = e[3];
        o1.x = e[4]; o1.y = e[5]; o1.z = e[6]; o1.w = e[7];
        *(float4*)(attn + rbase + c0) = o0;
        *(float4*)(attn + rbase + c0 + 4) = o1;
        *(short8*)(&P[rbase + c0]) = pb;
    } else {
        *(float4*)(attn + rbase + c0) = zf;
        *(float4*)(attn + rbase + c0 + 4) = zf;
        *(short8*)(&P[rbase + c0]) = zp;
    }
}

// ---------------------------------------------------------------- PV --------
// BK=64 [128][64] swizzled LDS, 1 barrier per K-tile.
__global__ void pv_kernel(const unsigned short* __restrict__ P,
                          const unsigned short* __restrict__ Vt,
                          const int* __restrict__ lens, float* __restrict__ seq) {
    const int log_id = xcd_swz(blockIdx.x, B_ * (S_ / 128) * (D_ / 128));
    const int b = log_id >> 7;
    const int rem = log_id & 127;
    const int q0 = (rem >> 3) * 128;
    const int n0 = (rem & 7) * 128;
    const int len = lens[b];
    const int tid = threadIdx.x;

    if (q0 >= len) {
        const float4 zf = {0.f, 0.f, 0.f, 0.f};
#pragma unroll
        for (int it = 0; it < 16; ++it) {
            int flat = it * 1024 + tid * 4;
            int r = flat >> 7, c = flat & 127;
            *(float4*)(&seq[(size_t)(b * S_ + q0 + r) * D_ + n0 + c]) = zf;
        }
        return;
    }

    __shared__ unsigned short As[2][128 * 64];
    __shared__ unsigned short Bs[2][128 * 64];
    const int lane = tid & 63, w = tid >> 6;
    const int wr = w >> 1, wc = w & 1;
    const int g = lane >> 4, l15 = lane & 15;

    const char* Pbase = (const char*)(P + (size_t)(b * S_ + q0) * S_);
    const char* Vbase = (const char*)(Vt + ((size_t)b * D_ + n0) * S_);

    const int f0 = tid * 16;
    const int rs = f0 >> 7, cs = f0 & 127;
    const int csrc = cs ^ ((rs & 7) << 4);

    auto stage = [&](int buf, int kk) {
#pragma unroll
        for (int c = 0; c < 4; ++c) {
            gload16(Pbase + (size_t)(rs + c * 32) * (S_ * 2) + kk * 2 + csrc,
                    (char*)&As[buf][0] + c * 4096 + f0);
            gload16(Vbase + (size_t)(rs + c * 32) * (S_ * 2) + kk * 2 + csrc,
                    (char*)&Bs[buf][0] + c * 4096 + f0);
        }
    };

    f32x4 acc[4][4];
    const f32x4 z4 = {0.f, 0.f, 0.f, 0.f};
    for (int a = 0; a < 4; ++a)
        for (int b2 = 0; b2 < 4; ++b2) acc[a][b2] = z4;

    const int nkt = (q0 + 128) / 64;   // causal: only k <= q0+127 contribute

    stage(0, 0);
    pipe_sync();
    for (int T = 0; T < nkt; ++T) {
        const int cur = T & 1;
        if (T + 1 < nkt) stage(cur ^ 1, (T + 1) * 64);
#pragma unroll
        for (int ks = 0; ks < 2; ++ks) {
            const int colb = ks * 64 + g * 16;
            short8 a_frag[4], b_frag[4];
#pragma unroll
            for (int mf = 0; mf < 4; ++mf)
                a_frag[mf] = *(const short8*)((const char*)&As[cur][0]
                                              + swz((wr * 64 + mf * 16 + l15) * 128 + colb));
#pragma unroll
            for (int nf = 0; nf < 4; ++nf)
                b_frag[nf] = *(const short8*)((const char*)&Bs[cur][0]
                                              + swz((wc * 64 + nf * 16 + l15) * 128 + colb));
            __builtin_amdgcn_s_setprio(1);
#pragma unroll
            for (int mf = 0; mf < 4; ++mf)
#pragma unroll
                for (int nf = 0; nf < 4; ++nf)
                    acc[mf][nf] = __builtin_amdgcn_mfma_f32_16x16x32_bf16(
                        a_frag[mf], b_frag[nf], acc[mf][nf], 0, 0, 0);
            __builtin_amdgcn_s_setprio(0);
        }
        pipe_sync();
    }

#pragma unroll
    for (int mf = 0; mf < 4; ++mf) {
#pragma unroll
        for (int nf = 0; nf < 4; ++nf) {
            int gq = q0 + wr * 64 + mf * 16 + 4 * g;
            int gn = n0 + wc * 64 + nf * 16 + l15;
#pragma unroll
            for (int i = 0; i < 4; ++i)
                seq[(size_t)(b * S_ + gq + i) * D_ + gn] = acc[mf][nf][i];
        }
    }
}

// ---------------------------------------------------------------- launch ----
extern "C" void kernel_launch(void* const* d_in, const int* in_sizes, int n_in,
                              void* d_out, int out_size, void* d_ws, size_t ws_size,
                              hipStream_t stream) {
    const float* q = (const float*)d_in[0];
    const float* k = (const float*)d_in[1];
    const float* v = (const float*)d_in[2];
    const unsigned char* pm = (const unsigned char*)d_in[3];
    const float* Wq = (const float*)d_in[5];
    const float* bq = (const float*)d_in[6];
    const float* Wk = (const float*)d_in[7];
    const float* bk = (const float*)d_in[8];
    const float* Wv = (const float*)d_in[9];
    const float* bv = (const float*)d_in[10];

    float* seq = (float*)d_out;
    float* attn = seq + (size_t)B_ * S_ * D_;

    char* ws = (char*)d_ws;
    int* lens = (int*)ws;
    unsigned short* Qb = (unsigned short*)(ws + 256);
    unsigned short* Kb = Qb + (size_t)B_ * S_ * D_;
    unsigned short* Vt = Kb + (size_t)B_ * S_ * D_;
    unsigned short* Xb = Vt + (size_t)B_ * D_ * S_;   // 3x B*S*D
    unsigned short* Wb = Xb + 3ull * B_ * S_ * D_;    // 3x D*D
    unsigned short* P = Qb;   // reuse Q+K region (exactly B*S*S bf16) after scores

    const size_t need = 256 + 6ull * B_ * S_ * D_ * 2 + 3ull * D_ * D_ * 2;

    lengths_kernel<<<1, 256, 0, stream>>>(pm, lens);

    if (ws_size >= need) {
        convert_all_kernel<<<dim3(B_ * S_ * D_ / 2048, 1, 6), 256, 0, stream>>>(
            q, k, v, Wq, Wk, Wv, Xb, Wb);
        proj2_kernel<<<dim3(3 * (B_ * S_ / 256) * (D_ / 256)), 512, 0, stream>>>(
            Xb, Wb, bq, bk, bv, Qb, Kb, Vt);
    } else {
        proj_kernel<<<dim3(D_ / 128, (B_ * S_) / 128, 3), 256, 0, stream>>>(
            q, k, v, Wq, Wk, Wv, bq, bk, bv, Qb, Kb, Vt);
    }

    scores_kernel<<<dim3(136 * B_), 256, 0, stream>>>(Qb, Kb, lens, attn);
    softmax_kernel<<<dim3(B_ * S_), 256, 0, stream>>>(lens, attn, P);
    pv_kernel<<<dim3(B_ * (S_ / 128) * (D_ / 128)), 256, 0, stream>>>(P, Vt, lens, seq);
}